// Round 1
// 1201.540 us; speedup vs baseline: 1.0758x; 1.0758x over previous
//
#include <hip/hip_runtime.h>
#include <hip/hip_bf16.h>

#define BB 32
#define NN 2048
#define DD 512
#define DGG 1024
#define CC 32          // scan chunks per sequence
#define LLEN 64        // scan chunk length (CC*LLEN == NN)

typedef short bf16x8 __attribute__((ext_vector_type(8)));
typedef float f32x4  __attribute__((ext_vector_type(4)));

__device__ __forceinline__ unsigned short f2bf(float f){
    __hip_bfloat16 h = __float2bfloat16(f);
    return *reinterpret_cast<unsigned short*>(&h);
}
__device__ __forceinline__ float bf2f(unsigned short u){
    unsigned int x = ((unsigned int)u) << 16;
    return __uint_as_float(x);
}
__device__ __forceinline__ float sigm(float x){ return 1.0f/(1.0f + __expf(-x)); }

// async global->LDS, 16B per lane; LDS dest = wave-uniform base + lane*16 (m97/m104)
__device__ __forceinline__ void gl_lds16(const unsigned short* g, unsigned short* l){
    __builtin_amdgcn_global_load_lds(
        (const __attribute__((address_space(1))) unsigned int*)g,
        (__attribute__((address_space(3))) unsigned int*)l, 16, 0, 0);
}

// ---------------------------------------------------------------------------
// Weight prep: transpose + cast  in[K][N] fp32  ->  out[N][K] bf16.
// ---------------------------------------------------------------------------
__global__ __launch_bounds__(256)
void wt_prep(const float* __restrict__ in, unsigned short* __restrict__ out,
             int K, int N)
{
    __shared__ float t[32][33];
    const int tid = threadIdx.x;
    const int r = tid >> 3;            // 0..31
    const int c = (tid & 7) << 2;      // 0,4,..,28
    const int n0 = blockIdx.x * 32;
    const int k0 = blockIdx.y * 32;
    float4 v = *(const float4*)(in + (size_t)(k0 + r) * N + n0 + c);
    t[r][c] = v.x; t[r][c+1] = v.y; t[r][c+2] = v.z; t[r][c+3] = v.w;
    __syncthreads();
    ushort4 o;
    o.x = f2bf(t[c+0][r]); o.y = f2bf(t[c+1][r]);
    o.z = f2bf(t[c+2][r]); o.w = f2bf(t[c+3][r]);
    *(ushort4*)(out + (size_t)(n0 + r) * K + k0 + c) = o;
}

// fp32 -> bf16 cast, 4 elems/thread
__global__ __launch_bounds__(256)
void cast_bf16(const float* __restrict__ in, unsigned short* __restrict__ out)
{
    size_t i = ((size_t)blockIdx.x * 256 + threadIdx.x) * 4;
    float4 v = *(const float4*)(in + i);
    ushort4 o;
    o.x = f2bf(v.x); o.y = f2bf(v.y); o.z = f2bf(v.z); o.w = f2bf(v.w);
    *(ushort4*)(out + i) = o;
}

// ---------------------------------------------------------------------------
// gemm256: 256x256 tile, BK=32, 3-deep pipelined global_load_lds staging with
// counted vmcnt (never 0 in main loop), swizzled LDS reads (2-way conflicts),
// XCD-aware 1-D grid swizzle.  A[M][K] bf16, Bt[Nn][K] bf16 (pre-transposed).
// 512 threads = 8 waves (2M x 4N), each wave owns a 128x64 output sub-tile
// (acc[8][4] of 16x16x32 MFMA fragments).
//   MODE 0: out0 = A@B + bias
//   MODE 1: out0 = silu(A@B + bias)
//   MODE 2: out0 = sigmoid(A@B + bias)
//   MODE 3: fv=sigm(+bias); lam=lb+(1-lb)*fv -> out0; u=(1-lam)*staged -> out1
//   MODE 4: out0 = staged * (A@B + bias)
// staged may alias out0/out1 (same-thread read-then-write per element).
// ---------------------------------------------------------------------------
template<int MODE, int K, int Nn>
__global__ __launch_bounds__(512, 2)
void gemm256(const unsigned short* __restrict__ A,
             const unsigned short* __restrict__ Bt,
             const float* __restrict__ bias,
             const unsigned short* __restrict__ staged,
             unsigned short* __restrict__ out0,
             unsigned short* __restrict__ out1,
             const int* __restrict__ lbp, int Mtiles)
{
    constexpr int NT   = K / 32;       // K-tiles
    constexpr int Ntl  = Nn / 256;     // n-tiles
    constexpr int TILE = 256 * 32;     // elements per LDS buffer (16 KiB)
    __shared__ unsigned short AsE[3 * TILE];   // 48 KiB
    __shared__ unsigned short BsE[3 * TILE];   // 48 KiB

    const int tid  = threadIdx.x;
    const int wave = tid >> 6;
    const int lane = tid & 63;
    const int lm   = lane & 15;
    const int quad = lane >> 4;
    const int wr   = (wave >> 2) * 128;   // wave row offset in 256-row tile
    const int wc   = (wave & 3) * 64;     // wave col offset in 256-col tile

    // XCD-aware bijective swizzle (nwg % 8 == 0 for all shapes here).
    // Logical order is n-fast so consecutive tiles on an XCD reuse the A panel.
    const int nwg = Mtiles * Ntl;
    const int h   = blockIdx.x;
    const int wg  = (h & 7) * (nwg >> 3) + (h >> 3);
    const int bm  = wg / Ntl;
    const int bn  = wg - bm * Ntl;
    const size_t m0 = (size_t)bm * 256;
    const int    n0 = bn * 256;

    // ---- staging addresses.  One gl_lds issue = 512 threads x 16B = 128 rows
    // of 64B.  LDS write is linear; the global SOURCE is pre-swizzled so that
    // LDS 16B-slot s holds global k-slot s ^ ((row>>1)&3)  (rule #21).
    const int lrow  = lane >> 2;                               // row within wave's 16
    const int oslot = ((lane & 3) ^ ((lane >> 3) & 3)) << 3;   // element offset in row
    const unsigned short* gA = A  + (m0 + (size_t)(wave * 16 + lrow)) * K + oslot;
    const unsigned short* gB = Bt + ((size_t)n0 + wave * 16 + lrow) * K + oslot;
    unsigned short* lA = &AsE[(wave * 16) * 32];   // wave-uniform LDS bases
    unsigned short* lB = &BsE[(wave * 16) * 32];
    // ds_read applies the same involution: slot read = quad ^ ((row>>1)&3)
    const int aslot = (quad ^ ((lm >> 1) & 3)) << 3;

    f32x4 acc[8][4];
    const f32x4 zero = {0.f, 0.f, 0.f, 0.f};
    #pragma unroll
    for (int i = 0; i < 8; ++i)
        #pragma unroll
        for (int j = 0; j < 4; ++j) acc[i][j] = zero;

    #define STAGE(kt, bs) do {                                   \
        const unsigned short* ga_ = gA + (kt) * 32;              \
        const unsigned short* gb_ = gB + (kt) * 32;              \
        unsigned short* la_ = lA + (bs) * TILE;                  \
        unsigned short* lb_ = lB + (bs) * TILE;                  \
        gl_lds16(ga_,           la_);                            \
        gl_lds16(ga_ + 128 * K, la_ + 128 * 32);                 \
        gl_lds16(gb_,           lb_);                            \
        gl_lds16(gb_ + 128 * K, lb_ + 128 * 32);                 \
    } while (0)

    // prologue: tiles 0,1 in flight; wait for tile 0 only (4 newest stay out)
    STAGE(0, 0);
    STAGE(1, 1);
    asm volatile("s_waitcnt vmcnt(4)" ::: "memory");
    __builtin_amdgcn_s_barrier();

    int br = 0;                        // buffer holding tile t
    for (int t = 0; t < NT; ++t) {
        int bs = br + 2; if (bs >= 3) bs -= 3;       // buffer for tile t+2
        if (t + 2 < NT) STAGE(t + 2, bs);            // freed at iter t-1's barrier

        const unsigned short* Ab = &AsE[br * TILE];
        const unsigned short* Bb = &BsE[br * TILE];
        bf16x8 a[8], b[4];
        #pragma unroll
        for (int mi = 0; mi < 8; ++mi)
            a[mi] = *(const bf16x8*)&Ab[(wr + mi * 16 + lm) * 32 + aslot];
        #pragma unroll
        for (int ni = 0; ni < 4; ++ni)
            b[ni] = *(const bf16x8*)&Bb[(wc + ni * 16 + lm) * 32 + aslot];
        #pragma unroll
        for (int mi = 0; mi < 8; ++mi)
            #pragma unroll
            for (int ni = 0; ni < 4; ++ni)
                acc[mi][ni] = __builtin_amdgcn_mfma_f32_16x16x32_bf16(
                    a[mi], b[ni], acc[mi][ni], 0, 0, 0);

        // counted wait: tile t+1 guaranteed landed; tile t+2's 4 loads stay
        // in flight across the barrier.  Drain only at the tail.
        if (t + 2 < NT)      asm volatile("s_waitcnt vmcnt(4)" ::: "memory");
        else if (t + 1 < NT) asm volatile("s_waitcnt vmcnt(0)" ::: "memory");
        if (t + 1 < NT) __builtin_amdgcn_s_barrier();
        br += 1; if (br == 3) br = 0;
    }
    #undef STAGE

    // epilogue.  C/D: row=(lane>>4)*4+r, col=lane&15 (m89-verified)
    float lbv = 0.f;
    if constexpr (MODE == 3) lbv = (float)(*lbp);

    float bcol[4];
    #pragma unroll
    for (int ni = 0; ni < 4; ++ni) bcol[ni] = bias[n0 + wc + ni * 16 + lm];

    #pragma unroll
    for (int mi = 0; mi < 8; ++mi) {
        #pragma unroll
        for (int ni = 0; ni < 4; ++ni) {
            const int col = n0 + wc + ni * 16 + lm;
            #pragma unroll
            for (int r = 0; r < 4; ++r) {
                const size_t row = m0 + wr + mi * 16 + quad * 4 + r;
                const size_t oidx = row * Nn + col;
                float v = acc[mi][ni][r] + bcol[ni];
                if constexpr (MODE == 0) {
                    out0[oidx] = f2bf(v);
                } else if constexpr (MODE == 1) {
                    out0[oidx] = f2bf(v * sigm(v));
                } else if constexpr (MODE == 2) {
                    out0[oidx] = f2bf(sigm(v));
                } else if constexpr (MODE == 3) {
                    float fv = sigm(v);
                    float lamv = lbv + (1.f - lbv) * fv;
                    float si = bf2f(staged[oidx]);
                    out0[oidx] = f2bf(lamv);
                    out1[oidx] = f2bf((1.f - lamv) * si);
                } else { // MODE 4
                    out0[oidx] = f2bf(bf2f(staged[oidx]) * v);
                }
            }
        }
    }
}

// ---------------------------------------------------------------------------
// Scan pass 1: per (b,chunk,d) aggregates in one ascending pass.
// ---------------------------------------------------------------------------
__global__ __launch_bounds__(512)
void scan_agg(const unsigned short* __restrict__ lam, const unsigned short* __restrict__ u,
              float* __restrict__ Aarr, float* __restrict__ Vf, float* __restrict__ Vr)
{
    int bc = blockIdx.x;             // b*CC + c
    int b = bc >> 5, c = bc & 31;
    int d = threadIdx.x;
    size_t base = ((size_t)b * NN + c * LLEN) * DD + d;
    float A = 1.f, vf = 0.f, vr = 0.f;
    for (int t = 0; t < LLEN; ++t) {
        float lv = bf2f(lam[base + (size_t)t * DD]);
        float uv = bf2f(u[base + (size_t)t * DD]);
        vf = lv * vf + uv;
        vr += uv * A;
        A *= lv;
    }
    size_t o = (size_t)bc * DD + d;
    Aarr[o] = A; Vf[o] = vf; Vr[o] = vr;
}

__global__ __launch_bounds__(256)
void scan_comb(const float* __restrict__ Aarr, const float* __restrict__ Vf,
               const float* __restrict__ Vr, float* __restrict__ cf, float* __restrict__ cr)
{
    int g = blockIdx.x * 256 + threadIdx.x;
    int b = g >> 9, d = g & 511;
    float S = 0.f;
    for (int c = 0; c < CC; ++c) {
        size_t o = (size_t)(b * CC + c) * DD + d;
        cf[o] = S;
        S = Vf[o] + Aarr[o] * S;
    }
    S = 0.f;
    for (int c = CC - 1; c >= 0; --c) {
        size_t o = (size_t)(b * CC + c) * DD + d;
        cr[o] = S;
        S = Vr[o] + Aarr[o] * S;
    }
}

__global__ __launch_bounds__(256)
void scan_final(const unsigned short* __restrict__ lam, const unsigned short* __restrict__ u,
                const float* __restrict__ cf, const float* __restrict__ cr,
                float* __restrict__ h)
{
    int bid = blockIdx.x;            // b*64 + c*2 + dhalf
    int dh = bid & 1, c = (bid >> 1) & 31, b = bid >> 6;
    int d = dh * 256 + threadIdx.x;
    size_t base = ((size_t)b * NN + c * LLEN) * DD + d;
    size_t co   = (size_t)(b * CC + c) * DD + d;

    float hbuf[LLEN];
    float hf = cf[co];
    #pragma unroll
    for (int t = 0; t < LLEN; ++t) {
        float lv = bf2f(lam[base + (size_t)t * DD]);
        float uv = bf2f(u[base + (size_t)t * DD]);
        hf = lv * hf + uv;
        hbuf[t] = hf;
    }
    float hr = cr[co];
    #pragma unroll
    for (int t = LLEN - 1; t >= 0; --t) {
        float lv = bf2f(lam[base + (size_t)t * DD]);
        float uv = bf2f(u[base + (size_t)t * DD]);
        hr = lv * hr + uv;
        h[base + (size_t)t * DD] = hbuf[t] + hr;
    }
}

// hg = h * rsqrt(mean(h^2)+1e-6) * g   (bf16 out; in-place over g safe)
__global__ __launch_bounds__(256)
void rms_mul(const float* __restrict__ h, const unsigned short* __restrict__ g,
             unsigned short* __restrict__ hg)
{
    int row = blockIdx.x;
    size_t base = (size_t)row * DD;
    int tid = threadIdx.x, col = tid * 2;
    float2 v = *(const float2*)&h[base + col];
    float ss = v.x * v.x + v.y * v.y;
    #pragma unroll
    for (int off = 32; off > 0; off >>= 1) ss += __shfl_down(ss, off);
    __shared__ float ps[4];
    __shared__ float scale_s;
    if ((tid & 63) == 0) ps[tid >> 6] = ss;
    __syncthreads();
    if (tid == 0) scale_s = rsqrtf((ps[0] + ps[1] + ps[2] + ps[3]) * (1.f / DD) + 1e-6f);
    __syncthreads();
    float sc = scale_s;
    ushort2 gv = *(const ushort2*)&g[base + col];
    ushort2 o;
    o.x = f2bf(v.x * sc * bf2f(gv.x));
    o.y = f2bf(v.y * sc * bf2f(gv.y));
    *(ushort2*)&hg[base + col] = o;
}

// out = xin + layernorm(y)*gam + bet ; optional bf16 copy of out -> outb
__global__ __launch_bounds__(256)
void add_ln(const float* __restrict__ xin, const unsigned short* __restrict__ y,
            const float* __restrict__ gam, const float* __restrict__ bet,
            float* __restrict__ out, unsigned short* __restrict__ outb)
{
    int row = blockIdx.x;
    size_t base = (size_t)row * DD;
    int tid = threadIdx.x, col = tid * 2;
    ushort2 yv = *(const ushort2*)&y[base + col];
    float vx = bf2f(yv.x), vy = bf2f(yv.y);
    float s = vx + vy;
    float ss = vx * vx + vy * vy;
    #pragma unroll
    for (int off = 32; off > 0; off >>= 1) {
        s  += __shfl_down(s, off);
        ss += __shfl_down(ss, off);
    }
    __shared__ float ps[8];
    __shared__ float stats[2];
    if ((tid & 63) == 0) { ps[tid >> 6] = s; ps[4 + (tid >> 6)] = ss; }
    __syncthreads();
    if (tid == 0) {
        float st  = ps[0] + ps[1] + ps[2] + ps[3];
        float sst = ps[4] + ps[5] + ps[6] + ps[7];
        float mean = st * (1.f / DD);
        float var  = sst * (1.f / DD) - mean * mean;
        stats[0] = mean; stats[1] = rsqrtf(var + 1e-5f);
    }
    __syncthreads();
    float mean = stats[0], inv = stats[1];
    float2 xv = *(const float2*)&xin[base + col];
    float2 gv = *(const float2*)&gam[col];
    float2 bv = *(const float2*)&bet[col];
    float2 o;
    o.x = xv.x + (vx - mean) * inv * gv.x + bv.x;
    o.y = xv.y + (vy - mean) * inv * gv.y + bv.y;
    *(float2*)&out[base + col] = o;
    if (outb) {
        ushort2 ob; ob.x = f2bf(o.x); ob.y = f2bf(o.y);
        *(ushort2*)&outb[base + col] = ob;
    }
}

extern "C" void kernel_launch(void* const* d_in, const int* in_sizes, int n_in,
                              void* d_out, int out_size, void* d_ws, size_t ws_size,
                              hipStream_t stream)
{
    const float* x   = (const float*)d_in[0];
    const int*   lb  = (const int*)d_in[1];
    const float* Wi  = (const float*)d_in[2];
    const float* bi  = (const float*)d_in[3];
    const float* Wf  = (const float*)d_in[4];
    const float* bfp = (const float*)d_in[5];
    const float* Wg  = (const float*)d_in[6];
    const float* bg  = (const float*)d_in[7];
    const float* Wo  = (const float*)d_in[8];
    const float* bo  = (const float*)d_in[9];
    const float* tng = (const float*)d_in[10];
    const float* tnb = (const float*)d_in[11];
    const float* fng = (const float*)d_in[12];
    const float* fnb = (const float*)d_in[13];
    const float* W1  = (const float*)d_in[14];
    const float* b1  = (const float*)d_in[15];
    const float* W2  = (const float*)d_in[16];
    const float* b2  = (const float*)d_in[17];
    const float* W3  = (const float*)d_in[18];
    const float* b3  = (const float*)d_in[19];

    // ---- ws layout: [bf16 transposed weights | 4 bf16 slabs | fp32 aggregates] ----
    unsigned short* wbase = (unsigned short*)d_ws;
    unsigned short* WiT = wbase;                  // 512x512
    unsigned short* WfT = WiT + 262144;
    unsigned short* WgT = WfT + 262144;
    unsigned short* WoT = WgT + 262144;
    unsigned short* W1T = WoT + 262144;           // 1024x512
    unsigned short* W2T = W1T + 524288;
    unsigned short* W3T = W2T + 524288;           // 512x1024
    const size_t WTOT = 4 * 262144 + 3 * 524288;  // 2,621,440 shorts (5 MiB)

    wt_prep<<<dim3(16, 16), 256, 0, stream>>>(Wi, WiT, 512, 512);
    wt_prep<<<dim3(16, 16), 256, 0, stream>>>(Wf, WfT, 512, 512);
    wt_prep<<<dim3(16, 16), 256, 0, stream>>>(Wg, WgT, 512, 512);
    wt_prep<<<dim3(16, 16), 256, 0, stream>>>(Wo, WoT, 512, 512);
    wt_prep<<<dim3(32, 16), 256, 0, stream>>>(W1, W1T, 512, 1024);
    wt_prep<<<dim3(32, 16), 256, 0, stream>>>(W2, W2T, 512, 1024);
    wt_prep<<<dim3(16, 32), 256, 0, stream>>>(W3, W3T, 1024, 512);

    // per batch row: 4 bf16 slabs (NN*DD) + 5 fp32 aggregates (CC*DD)
    const size_t perB = (size_t)4 * NN * DD * 2 + (size_t)5 * CC * DD * 4;
    int Bch = 32;
    while (Bch > 1 && WTOT * 2 + (size_t)Bch * perB > ws_size) Bch >>= 1;
    const int nch = BB / Bch;

    const size_t slabE = (size_t)Bch * NN * DD;   // elements per bf16 slab

    for (int ch = 0; ch < nch; ++ch) {
        const size_t r0 = (size_t)ch * Bch * NN;  // first row of this chunk
        const int Mc = Bch * NN;
        const int Mt = Mc / 256;                  // 256-row m-tiles
        const float* xc = x + r0 * DD;
        unsigned short* S0 = wbase + WTOT;
        unsigned short* S1 = S0 + slabE;
        unsigned short* S2 = S0 + 2 * slabE;
        unsigned short* S3 = S0 + 3 * slabE;
        float* small = (float*)(S0 + 4 * slabE);
        const size_t agg = (size_t)Bch * CC * DD;
        float* Aarr = small;
        float* VfP  = small + agg;
        float* VrP  = small + 2 * agg;
        float* cfP  = small + 3 * agg;
        float* crP  = small + 4 * agg;
        float* hout = (float*)d_out + r0 * DD;    // h -> xr -> final out

        // 0) x -> bf16 (S3)
        cast_bf16<<<Mc / 2, 256, 0, stream>>>(xc, S3);
        // 1) si = silu(x@Wi+bi) -> S0
        gemm256<1, 512, 512><<<Mt * 2, 512, 0, stream>>>(
            S3, WiT, bi, nullptr, S0, nullptr, nullptr, Mt);
        // 2) f-GEMM: lam -> S1, u = (1-lam)*si -> S0 (in-place over si)
        gemm256<3, 512, 512><<<Mt * 2, 512, 0, stream>>>(
            S3, WfT, bfp, S0, S1, S0, lb, Mt);
        // 3) g = sigm(x@Wg+bg) -> S2
        gemm256<2, 512, 512><<<Mt * 2, 512, 0, stream>>>(
            S3, WgT, bg, nullptr, S2, nullptr, nullptr, Mt);
        // 4-6) bidirectional chunked scan: lam(S1), u(S0) -> h (fp32, d_out region)
        scan_agg<<<Bch * CC, 512, 0, stream>>>(S1, S0, Aarr, VfP, VrP);
        scan_comb<<<(Bch * DD) / 256, 256, 0, stream>>>(Aarr, VfP, VrP, cfP, crP);
        scan_final<<<Bch * CC * 2, 256, 0, stream>>>(S1, S0, cfP, crP, hout);
        // 7) hg = rms_norm(h)*g -> S2 (in place)
        rms_mul<<<Mc, 256, 0, stream>>>(hout, S2, S2);
        // 8) y2 = hg@Wo + bo -> S0
        gemm256<0, 512, 512><<<Mt * 2, 512, 0, stream>>>(
            S2, WoT, bo, nullptr, S0, nullptr, nullptr, Mt);
        // 9) xr = x + LN(y2)*tn_g+tn_b -> hout (fp32) + S3 (bf16)
        add_ln<<<Mc, 256, 0, stream>>>(xc, S0, tng, tnb, hout, S3);
        // 10) s = silu(xr@W1+b1) -> S1
        gemm256<1, 512, 1024><<<Mt * 4, 512, 0, stream>>>(
            S3, W1T, b1, nullptr, S1, nullptr, nullptr, Mt);
        // 11) v = s * (xr@W2+b2) -> S1 (in place)
        gemm256<4, 512, 1024><<<Mt * 4, 512, 0, stream>>>(
            S3, W2T, b2, S1, S1, nullptr, nullptr, Mt);
        // 12) y4 = v@W3 + b3 -> S0
        gemm256<0, 1024, 512><<<Mt * 2, 512, 0, stream>>>(
            S1, W3T, b3, nullptr, S0, nullptr, nullptr, Mt);
        // 13) out = xr + LN(y4)*fn_g+fn_b (fp32, in place in d_out region)
        add_ln<<<Mc, 256, 0, stream>>>(hout, S0, fng, fnb, hout, nullptr);
    }
}